// Round 2
// baseline (478.263 us; speedup 1.0000x reference)
//
#include <hip/hip_runtime.h>
#include <hip/hip_bf16.h>

#define N_NODES 20000
#define N_EDGES 320000
#define HID 256

typedef __attribute__((ext_vector_type(8))) short bf16x8;   // 8 bf16 = 4 VGPRs (MFMA A/B frag)
typedef __attribute__((ext_vector_type(4))) float f32x4;    // MFMA C/D frag

__device__ __forceinline__ float bf2f(ushort u) {
  union { unsigned int i; float f; } v; v.i = ((unsigned int)u) << 16; return v.f;
}
__device__ __forceinline__ ushort f2bf(float f) {
  union { float f; unsigned int i; } v; v.f = f;
  unsigned int r = v.i + 0x7FFFu + ((v.i >> 16) & 1u);   // RNE
  return (ushort)(r >> 16);
}

// ---------------------------------------------------------------------------
// Runtime dtype detection (graph-safe: same kernels every call, data-driven).
// flags[0]=1 -> x/weights are fp32 (else bf16). flags[1]=1 -> edges int64.
// bf16 N(0,1) data: exponent field <= ~0x82, zero "wild" values.
// fp32 data read as ushorts: low halves are random mantissa bits -> ~44% have
// exponent >= 0x90. int64 indices (<2^31): every odd int32 slot is 0.
// ---------------------------------------------------------------------------
__global__ void detect_kernel(const void* x1, const void* ei1, int* flags) {
  __shared__ int cnt_wild, cnt_oddnz;
  if (threadIdx.x == 0) { cnt_wild = 0; cnt_oddnz = 0; }
  __syncthreads();
  const ushort* xu = (const ushort*)x1;
  int wild = 0;
#pragma unroll
  for (int k = 0; k < 4; k++) {
    ushort u = xu[threadIdx.x * 4 + k];
    int ex = (u >> 7) & 0xFF;
    if (ex >= 0x90) wild++;
  }
  if (wild) atomicAdd(&cnt_wild, wild);
  const int* ii = (const int*)ei1;
  if (ii[threadIdx.x * 2 + 1] != 0) atomicAdd(&cnt_oddnz, 1);
  __syncthreads();
  if (threadIdx.x == 0) {
    flags[0] = (cnt_wild > 64) ? 1 : 0;
    flags[1] = (cnt_oddnz < 8) ? 1 : 0;
  }
}

// Canonicalize x -> bf16. 4 elems/thread, vectorized both paths.
__global__ void cvt_x_kernel(const void* x0, const void* x1v,
                             ushort* o0, ushort* o1, const int* flags) {
  const void* x = blockIdx.y ? x1v : x0;
  ushort* o = blockIdx.y ? o1 : o0;
  int i4 = (blockIdx.x * 256 + threadIdx.x) * 4;
  if (i4 >= N_NODES * HID) return;
  if (flags[0]) {
    float4 v = *(const float4*)((const float*)x + i4);
    ushort4 w; w.x = f2bf(v.x); w.y = f2bf(v.y); w.z = f2bf(v.z); w.w = f2bf(v.w);
    *(ushort4*)(o + i4) = w;
  } else {
    *(ushort4*)(o + i4) = *(const ushort4*)((const ushort*)x + i4);
  }
}

// Canonicalize edge_index -> int32.
__global__ void cvt_ei_kernel(const void* e0, const void* e1,
                              int* o0, int* o1, const int* flags) {
  const void* e = blockIdx.y ? e1 : e0;
  int* o = blockIdx.y ? o1 : o0;
  int i = blockIdx.x * 256 + threadIdx.x;
  if (i >= 2 * N_EDGES) return;
  o[i] = flags[1] ? (int)((const long long*)e)[i] : ((const int*)e)[i];
}

// Canonicalize all weights/biases -> one packed bf16 buffer.
// Layout: W1[0] W2[65536] W3[131072] Wl[196608] b1[197888] b2[198144]
//         b3[198400] bl[198656]; total 198661 elems.
__global__ void cvt_w_kernel(const void* W1, const void* W2, const void* W3, const void* Wl,
                             const void* b1, const void* b2, const void* b3, const void* bl,
                             ushort* out, const int* flags) {
  int i = blockIdx.x * 256 + threadIdx.x;
  if (i >= 198661) return;
  const void* src; int off;
  if (i < 65536)       { src = W1; off = 0; }
  else if (i < 131072) { src = W2; off = 65536; }
  else if (i < 196608) { src = W3; off = 131072; }
  else if (i < 197888) { src = Wl; off = 196608; }
  else if (i < 198144) { src = b1; off = 197888; }
  else if (i < 198400) { src = b2; off = 198144; }
  else if (i < 198656) { src = b3; off = 198400; }
  else                 { src = bl; off = 198656; }
  int j = i - off;
  out[i] = flags[0] ? f2bf(((const float*)src)[j]) : ((const ushort*)src)[j];
}

// Zero all accumulated state (ws is poisoned 0xAA before every timed call).
__global__ void init_kernel(int* cnt0, int* cnt1, int* cur0, int* cur1,
                            float* t0, float* t1, float* s0, float* s1) {
  int i = blockIdx.x * blockDim.x + threadIdx.x;
  if (i < N_NODES) { cnt0[i] = 0; cnt1[i] = 0; cur0[i] = 0; cur1[i] = 0; t0[i] = 0.f; t1[i] = 0.f; }
  if (i < HID) { s0[i] = 0.f; s1[i] = 0.f; }
}

// In-degree histogram (dst side). deg = cnt + 1 (self loop).
__global__ void count_kernel(const int* ei0, const int* ei1, int* cnt0, int* cnt1) {
  int e = blockIdx.x * blockDim.x + threadIdx.x;
  if (e >= N_EDGES) return;
  const int* ei = blockIdx.y ? ei1 : ei0;
  int* cnt = blockIdx.y ? cnt1 : cnt0;
  atomicAdd(&cnt[ei[N_EDGES + e]], 1);
}

__global__ void dinv_kernel(const int* cnt0, const int* cnt1, float* dinv0, float* dinv1) {
  int i = blockIdx.x * blockDim.x + threadIdx.x;
  if (i >= N_NODES) return;
  const int* cnt = blockIdx.y ? cnt1 : cnt0;
  float* dinv = blockIdx.y ? dinv1 : dinv0;
  dinv[i] = rsqrtf((float)cnt[i] + 1.0f);
}

// Single-block exclusive scan -> CSR row_ptr. One block per branch.
__global__ void scan_kernel(const int* cnt0, const int* cnt1, int* rp0, int* rp1) {
  const int* cnt = blockIdx.x ? cnt1 : cnt0;
  int* rp = blockIdx.x ? rp1 : rp0;
  __shared__ int sd[1024];
  int tid = threadIdx.x;
  if (tid == 0) rp[0] = 0;
  int running = 0;
  for (int base = 0; base < N_NODES; base += 1024) {
    int i = base + tid;
    sd[tid] = (i < N_NODES) ? cnt[i] : 0;
    __syncthreads();
    for (int off = 1; off < 1024; off <<= 1) {
      int t2 = (tid >= off) ? sd[tid - off] : 0;
      __syncthreads();
      if (tid >= off) sd[tid] += t2;
      __syncthreads();
    }
    if (i < N_NODES) rp[i + 1] = running + sd[tid];
    running += sd[1023];
    __syncthreads();
  }
}

// Fill CSR (col + edge coef) and t[j] = sum_{e:src=j} dinv[dst]
// (t feeds the algebraic layer-3 shortcut: c_j = dinv_j*(t_j + dinv_j)).
__global__ void fill_kernel(const int* ei0, const int* ei1,
                            const float* dinv0, const float* dinv1,
                            const int* rp0, const int* rp1,
                            int* cur0, int* cur1,
                            int* col0, int* col1,
                            float* coef0, float* coef1,
                            float* t0, float* t1) {
  int e = blockIdx.x * blockDim.x + threadIdx.x;
  if (e >= N_EDGES) return;
  int b = blockIdx.y;
  const int* ei = b ? ei1 : ei0;
  const float* dinv = b ? dinv1 : dinv0;
  const int* rp = b ? rp1 : rp0;
  int* cur = b ? cur1 : cur0;
  int* col = b ? col1 : col0;
  float* coef = b ? coef1 : coef0;
  float* t = b ? t1 : t0;
  int src = ei[e], dst = ei[N_EDGES + e];
  int p = atomicAdd(&cur[dst], 1);
  int slot = rp[dst] + p;
  col[slot] = src;
  coef[slot] = dinv[src] * dinv[dst];
  atomicAdd(&t[src], dinv[dst]);
}

// C[M,256] = A[M,256] @ W[256,256], bf16 in/out, fp32 MFMA accumulate.
// Block 256 thr = 4 waves; 64x64 tile; BK=32; 16x16x32 bf16 MFMA.
// A/B frag layout (verified m89/m91): operand row = lane&15, k = (lane>>4)*8+j.
// C/D layout: col = lane&15, row = (lane>>4)*4 + reg.
__global__ __launch_bounds__(256) void gemm_kernel(
    const ushort* __restrict__ A0, const ushort* __restrict__ A1,
    const ushort* __restrict__ W,
    ushort* __restrict__ C0, ushort* __restrict__ C1) {
  const ushort* A = blockIdx.z ? A1 : A0;
  ushort* C = blockIdx.z ? C1 : C0;
  int m0 = blockIdx.x * 64;
  int n0 = blockIdx.y * 64;
  __shared__ ushort As[64][40];   // row stride 80 B (multiple of 16, not pow2)
  __shared__ ushort Bs[64][40];   // B^T tile: Bs[n][k] = W[k0+k][n0+n]
  int tid = threadIdx.x;
  int wave = tid >> 6, lane = tid & 63;
  int quad = lane >> 4, r16 = lane & 15;
  f32x4 acc0 = {0.f, 0.f, 0.f, 0.f}, acc1 = acc0, acc2 = acc0, acc3 = acc0;
  int la_row = tid >> 2;          // 0..63
  int la_off = (tid & 3) * 8;     // 0,8,16,24
  int lb_k = tid >> 3;            // 0..31
  int lb_n = (tid & 7) * 8;       // 0..56
  for (int k0 = 0; k0 < 256; k0 += 32) {
    int gr = m0 + la_row;
    int4 va = {0, 0, 0, 0};
    if (gr < N_NODES) va = *(const int4*)(A + gr * 256 + k0 + la_off);
    *(int4*)&As[la_row][la_off] = va;
    int4 vb = *(const int4*)(W + (k0 + lb_k) * 256 + n0 + lb_n);
    ushort tmp[8];
    *(int4*)tmp = vb;
#pragma unroll
    for (int j = 0; j < 8; j++) Bs[lb_n + j][lb_k] = tmp[j];
    __syncthreads();
    bf16x8 a  = *(const bf16x8*)&As[wave * 16 + r16][quad * 8];
    bf16x8 b0 = *(const bf16x8*)&Bs[r16][quad * 8];
    bf16x8 b1 = *(const bf16x8*)&Bs[16 + r16][quad * 8];
    bf16x8 b2 = *(const bf16x8*)&Bs[32 + r16][quad * 8];
    bf16x8 b3 = *(const bf16x8*)&Bs[48 + r16][quad * 8];
    acc0 = __builtin_amdgcn_mfma_f32_16x16x32_bf16(a, b0, acc0, 0, 0, 0);
    acc1 = __builtin_amdgcn_mfma_f32_16x16x32_bf16(a, b1, acc1, 0, 0, 0);
    acc2 = __builtin_amdgcn_mfma_f32_16x16x32_bf16(a, b2, acc2, 0, 0, 0);
    acc3 = __builtin_amdgcn_mfma_f32_16x16x32_bf16(a, b3, acc3, 0, 0, 0);
    __syncthreads();
  }
  int orow = m0 + wave * 16 + quad * 4;
#pragma unroll
  for (int r = 0; r < 4; r++) {
    int gr = orow + r;
    if (gr < N_NODES) {
      ushort* cp = C + gr * 256 + n0 + r16;
      cp[0]  = f2bf(acc0[r]);
      cp[16] = f2bf(acc1[r]);
      cp[32] = f2bf(acc2[r]);
      cp[48] = f2bf(acc3[r]);
    }
  }
}

// H[i] = relu( dinv_i^2 * XW[i] + sum_{e in CSR row i} coef[e]*XW[col[e]] + bias ).
// One 64-thread block per node; lane handles 4 features (ushort4 coalesced row).
__global__ __launch_bounds__(64) void agg_kernel(
    const ushort* __restrict__ XW0, const ushort* __restrict__ XW1,
    const float* __restrict__ dinv0, const float* __restrict__ dinv1,
    const int* __restrict__ rp0, const int* __restrict__ rp1,
    const int* __restrict__ col0, const int* __restrict__ col1,
    const float* __restrict__ coef0, const float* __restrict__ coef1,
    const ushort* __restrict__ bias,
    ushort* __restrict__ H0, ushort* __restrict__ H1) {
  int b = blockIdx.y;
  const ushort* XW = b ? XW1 : XW0;
  const float* dinv = b ? dinv1 : dinv0;
  const int* rp = b ? rp1 : rp0;
  const int* col = b ? col1 : col0;
  const float* coef = b ? coef1 : coef0;
  ushort* H = b ? H1 : H0;
  int i = blockIdx.x;
  int f4 = threadIdx.x * 4;
  float di = dinv[i];
  float self = di * di;
  ushort4 v = *(const ushort4*)(XW + i * 256 + f4);
  float a0 = self * bf2f(v.x), a1 = self * bf2f(v.y);
  float a2 = self * bf2f(v.z), a3 = self * bf2f(v.w);
  int e0 = rp[i], e1 = rp[i + 1];
  for (int e = e0; e < e1; e++) {
    int s = col[e];
    float c = coef[e];
    ushort4 u = *(const ushort4*)(XW + s * 256 + f4);
    a0 += c * bf2f(u.x); a1 += c * bf2f(u.y);
    a2 += c * bf2f(u.z); a3 += c * bf2f(u.w);
  }
  ushort4 bb = *(const ushort4*)(bias + f4);
  a0 = fmaxf(a0 + bf2f(bb.x), 0.f);
  a1 = fmaxf(a1 + bf2f(bb.y), 0.f);
  a2 = fmaxf(a2 + bf2f(bb.z), 0.f);
  a3 = fmaxf(a3 + bf2f(bb.w), 0.f);
  ushort4 o; o.x = f2bf(a0); o.y = f2bf(a1); o.z = f2bf(a2); o.w = f2bf(a3);
  *(ushort4*)(H + i * 256 + f4) = o;
}

// s[f] = sum_j c_j * H[j][f],  c_j = dinv_j*(t_j + dinv_j)  (layer-3 shortcut)
__global__ __launch_bounds__(256) void colsum_kernel(
    const ushort* __restrict__ H0, const ushort* __restrict__ H1,
    const float* __restrict__ dinv0, const float* __restrict__ dinv1,
    const float* __restrict__ t0, const float* __restrict__ t1,
    float* __restrict__ s0, float* __restrict__ s1) {
  int b = blockIdx.y;
  const ushort* H = b ? H1 : H0;
  const float* dinv = b ? dinv1 : dinv0;
  const float* t = b ? t1 : t0;
  float* s = b ? s1 : s0;
  int f = threadIdx.x;
  float acc = 0.f;
  for (int j = blockIdx.x; j < N_NODES; j += gridDim.x) {
    float dj = dinv[j];
    float c = dj * (t[j] + dj);
    acc += c * bf2f(H[j * 256 + f]);
  }
  atomicAdd(&s[f], acc);
}

// pooled = ((s0+s1) @ W3)/(2N) + b3 ;  out = pooled @ Wl + bl
// Output dtype follows detected input dtype (fp32 or bf16).
__global__ __launch_bounds__(256) void final_kernel(
    const float* __restrict__ s0, const float* __restrict__ s1,
    const ushort* __restrict__ W3, const ushort* __restrict__ b3,
    const ushort* __restrict__ Wl, const ushort* __restrict__ bl,
    void* __restrict__ out, const int* __restrict__ flags) {
  __shared__ float v[256];
  __shared__ float pooled[256];
  int t = threadIdx.x;
  v[t] = s0[t] + s1[t];
  __syncthreads();
  float acc = 0.f;
  for (int f = 0; f < 256; f++) acc += v[f] * bf2f(W3[f * 256 + t]);
  pooled[t] = acc * (1.0f / (2.0f * N_NODES)) + bf2f(b3[t]);
  __syncthreads();
  if (t < 5) {
    float o = bf2f(bl[t]);
    for (int h = 0; h < 256; h++) o += pooled[h] * bf2f(Wl[h * 5 + t]);
    if (flags[0]) ((float*)out)[t] = o;
    else ((ushort*)out)[t] = f2bf(o);
  }
}

extern "C" void kernel_launch(void* const* d_in, const int* in_sizes, int n_in,
                              void* d_out, int out_size, void* d_ws, size_t ws_size,
                              hipStream_t stream) {
  const void* x1 = d_in[0];
  const void* ei1 = d_in[1];
  const void* x2 = d_in[2];
  const void* ei2 = d_in[3];
  const void* W1 = d_in[4];
  const void* b1 = d_in[5];
  const void* W2 = d_in[6];
  const void* b2 = d_in[7];
  const void* W3 = d_in[8];
  const void* b3 = d_in[9];
  const void* Wl = d_in[10];
  const void* bl = d_in[11];

  char* p = (char*)d_ws;
  auto alloc = [&](size_t bytes) {
    char* r = p;
    p += (bytes + 255) & ~size_t(255);
    return r;
  };
  int* flags   = (int*)alloc(256);
  float* dinv0 = (float*)alloc(N_NODES * 4);
  float* dinv1 = (float*)alloc(N_NODES * 4);
  float* t0    = (float*)alloc(N_NODES * 4);
  float* t1    = (float*)alloc(N_NODES * 4);
  float* s0    = (float*)alloc(HID * 4);
  float* s1    = (float*)alloc(HID * 4);
  int* cnt0    = (int*)alloc(N_NODES * 4);
  int* cnt1    = (int*)alloc(N_NODES * 4);
  int* cur0    = (int*)alloc(N_NODES * 4);
  int* cur1    = (int*)alloc(N_NODES * 4);
  int* rp0     = (int*)alloc((N_NODES + 1) * 4);
  int* rp1     = (int*)alloc((N_NODES + 1) * 4);
  int* col0    = (int*)alloc(N_EDGES * 4);
  int* col1    = (int*)alloc(N_EDGES * 4);
  float* coef0 = (float*)alloc(N_EDGES * 4);
  float* coef1 = (float*)alloc(N_EDGES * 4);
  ushort* wbuf = (ushort*)alloc(198661 * 2);
  ushort* xw0  = (ushort*)alloc((size_t)N_NODES * HID * 2);
  ushort* xw1  = (ushort*)alloc((size_t)N_NODES * HID * 2);
  ushort* xc0  = (ushort*)alloc((size_t)N_NODES * HID * 2);
  ushort* xc1  = (ushort*)alloc((size_t)N_NODES * HID * 2);
  // Lifetime-based aliasing (keeps ws under ~53 MB):
  // ei32 lives only until fill_kernel; xw0 first written by gemm1 (later).
  int* ei32_0 = (int*)xw0;
  int* ei32_1 = ei32_0 + 2 * N_EDGES;
  // xc dead after gemm1 reads it; h first written by agg1 (after gemm1).
  ushort* h0 = xc0;
  ushort* h1 = xc1;

  ushort* Wc1 = wbuf + 0;
  ushort* Wc2 = wbuf + 65536;
  ushort* Wc3 = wbuf + 131072;
  ushort* Wlc = wbuf + 196608;
  ushort* bc1 = wbuf + 197888;
  ushort* bc2 = wbuf + 198144;
  ushort* bc3 = wbuf + 198400;
  ushort* blc = wbuf + 198656;

  // --- dtype detection + canonicalization ---
  detect_kernel<<<1, 256, 0, stream>>>(x1, ei1, flags);
  cvt_ei_kernel<<<dim3((2 * N_EDGES + 255) / 256, 2), 256, 0, stream>>>(
      ei1, ei2, ei32_0, ei32_1, flags);
  cvt_x_kernel<<<dim3(N_NODES * HID / 1024, 2), 256, 0, stream>>>(
      x1, x2, xc0, xc1, flags);
  cvt_w_kernel<<<(198661 + 255) / 256, 256, 0, stream>>>(
      W1, W2, W3, Wl, b1, b2, b3, bl, wbuf, flags);

  // --- graph prep ---
  init_kernel<<<(N_NODES + 255) / 256, 256, 0, stream>>>(cnt0, cnt1, cur0, cur1, t0, t1, s0, s1);
  count_kernel<<<dim3((N_EDGES + 255) / 256, 2), 256, 0, stream>>>(ei32_0, ei32_1, cnt0, cnt1);
  dinv_kernel<<<dim3((N_NODES + 255) / 256, 2), 256, 0, stream>>>(cnt0, cnt1, dinv0, dinv1);
  scan_kernel<<<2, 1024, 0, stream>>>(cnt0, cnt1, rp0, rp1);
  fill_kernel<<<dim3((N_EDGES + 255) / 256, 2), 256, 0, stream>>>(
      ei32_0, ei32_1, dinv0, dinv1, rp0, rp1, cur0, cur1, col0, col1, coef0, coef1, t0, t1);

  // Layer 1: xw = x @ W1 ; h = relu(agg(xw) + b1)
  gemm_kernel<<<dim3(313, 4, 2), 256, 0, stream>>>(xc0, xc1, Wc1, xw0, xw1);
  agg_kernel<<<dim3(N_NODES, 2), 64, 0, stream>>>(
      xw0, xw1, dinv0, dinv1, rp0, rp1, col0, col1, coef0, coef1, bc1, h0, h1);

  // Layer 2: xw = h @ W2 ; h = relu(agg(xw) + b2)
  gemm_kernel<<<dim3(313, 4, 2), 256, 0, stream>>>(h0, h1, Wc2, xw0, xw1);
  agg_kernel<<<dim3(N_NODES, 2), 64, 0, stream>>>(
      xw0, xw1, dinv0, dinv1, rp0, rp1, col0, col1, coef0, coef1, bc2, h0, h1);

  // Layer 3 + pool, collapsed: s = sum_j c_j h2_j ; out = ((s0+s1)W3/(2N)+b3) @ Wl + bl
  colsum_kernel<<<dim3(128, 2), 256, 0, stream>>>(h0, h1, dinv0, dinv1, t0, t1, s0, s1);
  final_kernel<<<1, 256, 0, stream>>>(s0, s1, Wc3, bc3, Wlc, blc, d_out, flags);
}

// Round 3
// 416.487 us; speedup vs baseline: 1.1483x; 1.1483x over previous
//
#include <hip/hip_runtime.h>
#include <hip/hip_bf16.h>

#define N_NODES 20000
#define N_EDGES 320000
#define HID 256

typedef __attribute__((ext_vector_type(8))) short bf16x8;   // 8 bf16 = 4 VGPRs (MFMA A/B frag)
typedef __attribute__((ext_vector_type(4))) float f32x4;    // MFMA C/D frag

__device__ __forceinline__ float bf2f(ushort u) {
  union { unsigned int i; float f; } v; v.i = ((unsigned int)u) << 16; return v.f;
}
__device__ __forceinline__ ushort f2bf(float f) {
  union { float f; unsigned int i; } v; v.f = f;
  unsigned int r = v.i + 0x7FFFu + ((v.i >> 16) & 1u);   // RNE
  return (ushort)(r >> 16);
}

// ---------------------------------------------------------------------------
// Runtime dtype detection (graph-safe, data-driven, runs every call).
// flags[0]=1 -> x/weights fp32 (else bf16). flags[1]=1 -> edges int64.
// ---------------------------------------------------------------------------
__global__ void detect_kernel(const void* x1, const void* ei1, int* flags) {
  __shared__ int cnt_wild, cnt_oddnz;
  if (threadIdx.x == 0) { cnt_wild = 0; cnt_oddnz = 0; }
  __syncthreads();
  const ushort* xu = (const ushort*)x1;
  int wild = 0;
#pragma unroll
  for (int k = 0; k < 4; k++) {
    ushort u = xu[threadIdx.x * 4 + k];
    int ex = (u >> 7) & 0xFF;
    if (ex >= 0x90) wild++;
  }
  if (wild) atomicAdd(&cnt_wild, wild);
  const int* ii = (const int*)ei1;
  if (ii[threadIdx.x * 2 + 1] != 0) atomicAdd(&cnt_oddnz, 1);
  __syncthreads();
  if (threadIdx.x == 0) {
    flags[0] = (cnt_wild > 64) ? 1 : 0;
    flags[1] = (cnt_oddnz < 8) ? 1 : 0;
  }
}

// Zero accumulated state (ws is poisoned 0xAA before every timed call).
__global__ void init_kernel(int* cnt0, int* cnt1, float* t0, float* t1,
                            float* s0, float* s1) {
  int i = blockIdx.x * blockDim.x + threadIdx.x;
  if (i < N_NODES) { cnt0[i] = 0; cnt1[i] = 0; t0[i] = 0.f; t1[i] = 0.f; }
  if (i < HID) { s0[i] = 0.f; s1[i] = 0.f; }
}

// Canonicalize edge_index -> int32 AND fused dst-histogram with rank capture:
// the atomicAdd return value IS the edge's rank within its dst bucket, so
// fill_kernel needs no second slot-atomic (halves total fabric atomics).
__global__ void cvt_ei_count_kernel(const void* e0, const void* e1,
                                    int* o0, int* o1,
                                    int* cnt0, int* cnt1,
                                    int* rank0, int* rank1, const int* flags) {
  int b = blockIdx.y;
  const void* e = b ? e1 : e0;
  int* o = b ? o1 : o0;
  int* cnt = b ? cnt1 : cnt0;
  int* rank = b ? rank1 : rank0;
  int i = blockIdx.x * 256 + threadIdx.x;
  if (i >= 2 * N_EDGES) return;
  int v = flags[1] ? (int)((const long long*)e)[i] : ((const int*)e)[i];
  o[i] = v;
  if (i >= N_EDGES) rank[i - N_EDGES] = atomicAdd(&cnt[v], 1);
}

// Canonicalize x -> bf16. 4 elems/thread, vectorized both paths.
__global__ void cvt_x_kernel(const void* x0, const void* x1v,
                             ushort* o0, ushort* o1, const int* flags) {
  const void* x = blockIdx.y ? x1v : x0;
  ushort* o = blockIdx.y ? o1 : o0;
  int i4 = (blockIdx.x * 256 + threadIdx.x) * 4;
  if (i4 >= N_NODES * HID) return;
  if (flags[0]) {
    float4 v = *(const float4*)((const float*)x + i4);
    ushort4 w; w.x = f2bf(v.x); w.y = f2bf(v.y); w.z = f2bf(v.z); w.w = f2bf(v.w);
    *(ushort4*)(o + i4) = w;
  } else {
    *(ushort4*)(o + i4) = *(const ushort4*)((const ushort*)x + i4);
  }
}

// Canonicalize all weights/biases -> one packed bf16 buffer.
// Layout: W1[0] W2[65536] W3[131072] Wl[196608] b1[197888] b2[198144]
//         b3[198400] bl[198656]; total 198661 elems.
__global__ void cvt_w_kernel(const void* W1, const void* W2, const void* W3, const void* Wl,
                             const void* b1, const void* b2, const void* b3, const void* bl,
                             ushort* out, const int* flags) {
  int i = blockIdx.x * 256 + threadIdx.x;
  if (i >= 198661) return;
  const void* src; int off;
  if (i < 65536)       { src = W1; off = 0; }
  else if (i < 131072) { src = W2; off = 65536; }
  else if (i < 196608) { src = W3; off = 131072; }
  else if (i < 197888) { src = Wl; off = 196608; }
  else if (i < 198144) { src = b1; off = 197888; }
  else if (i < 198400) { src = b2; off = 198144; }
  else if (i < 198656) { src = b3; off = 198400; }
  else                 { src = bl; off = 198656; }
  int j = i - off;
  out[i] = flags[0] ? f2bf(((const float*)src)[j]) : ((const ushort*)src)[j];
}

__global__ void dinv_kernel(const int* cnt0, const int* cnt1, float* dinv0, float* dinv1) {
  int i = blockIdx.x * blockDim.x + threadIdx.x;
  if (i >= N_NODES) return;
  const int* cnt = blockIdx.y ? cnt1 : cnt0;
  float* dinv = blockIdx.y ? dinv1 : dinv0;
  dinv[i] = rsqrtf((float)cnt[i] + 1.0f);
}

// Exclusive scan -> CSR row_ptr. One 1024-thread block per branch; each thread
// owns 20 contiguous counts (register prefix) + one 10-step LDS scan of totals.
__global__ __launch_bounds__(1024) void scan_kernel(const int* cnt0, const int* cnt1,
                                                    int* rp0, int* rp1) {
  const int* cnt = blockIdx.x ? cnt1 : cnt0;
  int* rp = blockIdx.x ? rp1 : rp0;
  __shared__ int sd[1024];
  int tid = threadIdx.x;
  int base = tid * 20;
  int pref[20];
  int run = 0;
#pragma unroll
  for (int k = 0; k < 20; k++) {
    int i = base + k;
    run += (i < N_NODES) ? cnt[i] : 0;
    pref[k] = run;              // inclusive prefix within this thread's chunk
  }
  sd[tid] = run;
  __syncthreads();
  for (int off = 1; off < 1024; off <<= 1) {
    int v = (tid >= off) ? sd[tid - off] : 0;
    __syncthreads();
    sd[tid] += v;
    __syncthreads();
  }
  int offset = sd[tid] - run;   // exclusive offset for this chunk
  if (tid == 0) rp[0] = 0;
#pragma unroll
  for (int k = 0; k < 20; k++) {
    int i = base + k;
    if (i < N_NODES) rp[i + 1] = offset + pref[k];
  }
}

// Fill CSR (col + edge coef) using precomputed rank (NO slot atomic), and
// t[j] = sum_{e:src=j} dinv[dst] (feeds layer-3 shortcut c_j = dinv_j*(t_j+dinv_j)).
__global__ void fill_kernel(const int* ei0, const int* ei1,
                            const float* dinv0, const float* dinv1,
                            const int* rp0, const int* rp1,
                            const int* rank0, const int* rank1,
                            int* col0, int* col1,
                            float* coef0, float* coef1,
                            float* t0, float* t1) {
  int e = blockIdx.x * blockDim.x + threadIdx.x;
  if (e >= N_EDGES) return;
  int b = blockIdx.y;
  const int* ei = b ? ei1 : ei0;
  const float* dinv = b ? dinv1 : dinv0;
  const int* rp = b ? rp1 : rp0;
  const int* rank = b ? rank1 : rank0;
  int* col = b ? col1 : col0;
  float* coef = b ? coef1 : coef0;
  float* t = b ? t1 : t0;
  int src = ei[e], dst = ei[N_EDGES + e];
  int slot = rp[dst] + rank[e];
  float dd = dinv[dst];
  col[slot] = src;
  coef[slot] = dinv[src] * dd;
  atomicAdd(&t[src], dd);
}

// C[M,256] = A[M,256] @ W[256,256], bf16 in/out, fp32 MFMA accumulate.
// Block 256 thr = 4 waves; 64x64 tile; BK=32; 16x16x32 bf16 MFMA.
// A/B frag: operand row = lane&15, k = (lane>>4)*8+j. C/D: col=lane&15, row=(lane>>4)*4+reg.
__global__ __launch_bounds__(256) void gemm_kernel(
    const ushort* __restrict__ A0, const ushort* __restrict__ A1,
    const ushort* __restrict__ W,
    ushort* __restrict__ C0, ushort* __restrict__ C1) {
  const ushort* A = blockIdx.z ? A1 : A0;
  ushort* C = blockIdx.z ? C1 : C0;
  int m0 = blockIdx.x * 64;
  int n0 = blockIdx.y * 64;
  __shared__ ushort As[64][40];   // row stride 80 B (multiple of 16, not pow2)
  __shared__ ushort Bs[64][40];   // B^T tile: Bs[n][k] = W[k0+k][n0+n]
  int tid = threadIdx.x;
  int wave = tid >> 6, lane = tid & 63;
  int quad = lane >> 4, r16 = lane & 15;
  f32x4 acc0 = {0.f, 0.f, 0.f, 0.f}, acc1 = acc0, acc2 = acc0, acc3 = acc0;
  int la_row = tid >> 2;          // 0..63
  int la_off = (tid & 3) * 8;     // 0,8,16,24
  int lb_k = tid >> 3;            // 0..31
  int lb_n = (tid & 7) * 8;       // 0..56
  for (int k0 = 0; k0 < 256; k0 += 32) {
    int gr = m0 + la_row;
    int4 va = {0, 0, 0, 0};
    if (gr < N_NODES) va = *(const int4*)(A + gr * 256 + k0 + la_off);
    *(int4*)&As[la_row][la_off] = va;
    int4 vb = *(const int4*)(W + (k0 + lb_k) * 256 + n0 + lb_n);
    ushort tmp[8];
    *(int4*)tmp = vb;
#pragma unroll
    for (int j = 0; j < 8; j++) Bs[lb_n + j][lb_k] = tmp[j];
    __syncthreads();
    bf16x8 a  = *(const bf16x8*)&As[wave * 16 + r16][quad * 8];
    bf16x8 b0 = *(const bf16x8*)&Bs[r16][quad * 8];
    bf16x8 b1 = *(const bf16x8*)&Bs[16 + r16][quad * 8];
    bf16x8 b2 = *(const bf16x8*)&Bs[32 + r16][quad * 8];
    bf16x8 b3 = *(const bf16x8*)&Bs[48 + r16][quad * 8];
    acc0 = __builtin_amdgcn_mfma_f32_16x16x32_bf16(a, b0, acc0, 0, 0, 0);
    acc1 = __builtin_amdgcn_mfma_f32_16x16x32_bf16(a, b1, acc1, 0, 0, 0);
    acc2 = __builtin_amdgcn_mfma_f32_16x16x32_bf16(a, b2, acc2, 0, 0, 0);
    acc3 = __builtin_amdgcn_mfma_f32_16x16x32_bf16(a, b3, acc3, 0, 0, 0);
    __syncthreads();
  }
  int orow = m0 + wave * 16 + quad * 4;
#pragma unroll
  for (int r = 0; r < 4; r++) {
    int gr = orow + r;
    if (gr < N_NODES) {
      ushort* cp = C + gr * 256 + n0 + r16;
      cp[0]  = f2bf(acc0[r]);
      cp[16] = f2bf(acc1[r]);
      cp[32] = f2bf(acc2[r]);
      cp[48] = f2bf(acc3[r]);
    }
  }
}

// H[i] = relu( dinv_i^2 * XW[i] + sum_{e in CSR row i} coef[e]*XW[col[e]] + bias ).
// 256-thr block = 4 waves = 4 nodes (32 waves/CU possible); lane owns 4 features.
// Edge loop unrolled x4 with independent accumulators -> 4 row-gathers in flight.
__global__ __launch_bounds__(256) void agg_kernel(
    const ushort* __restrict__ XW0, const ushort* __restrict__ XW1,
    const float* __restrict__ dinv0, const float* __restrict__ dinv1,
    const int* __restrict__ rp0, const int* __restrict__ rp1,
    const int* __restrict__ col0, const int* __restrict__ col1,
    const float* __restrict__ coef0, const float* __restrict__ coef1,
    const ushort* __restrict__ bias,
    ushort* __restrict__ H0, ushort* __restrict__ H1) {
  int b = blockIdx.y;
  const ushort* XW = b ? XW1 : XW0;
  const float* dinv = b ? dinv1 : dinv0;
  const int* rp = b ? rp1 : rp0;
  const int* col = b ? col1 : col0;
  const float* coef = b ? coef1 : coef0;
  ushort* H = b ? H1 : H0;
  int wave = threadIdx.x >> 6, lane = threadIdx.x & 63;
  int i = blockIdx.x * 4 + wave;          // 20000 = 5000*4, exact
  int f4 = lane * 4;
  float di = dinv[i];
  float self = di * di;
  ushort4 v = *(const ushort4*)(XW + i * 256 + f4);
  float a0 = self * bf2f(v.x), a1 = self * bf2f(v.y);
  float a2 = self * bf2f(v.z), a3 = self * bf2f(v.w);
  float c0_ = 0.f, c1_ = 0.f, c2_ = 0.f, c3_ = 0.f;   // second accumulator set
  int e0 = rp[i], e1 = rp[i + 1];
  int e = e0;
  for (; e + 3 < e1; e += 4) {
    int s0 = col[e], s1 = col[e + 1], s2 = col[e + 2], s3 = col[e + 3];
    float w0 = coef[e], w1 = coef[e + 1], w2 = coef[e + 2], w3 = coef[e + 3];
    ushort4 u0 = *(const ushort4*)(XW + s0 * 256 + f4);
    ushort4 u1 = *(const ushort4*)(XW + s1 * 256 + f4);
    ushort4 u2 = *(const ushort4*)(XW + s2 * 256 + f4);
    ushort4 u3 = *(const ushort4*)(XW + s3 * 256 + f4);
    a0 += w0 * bf2f(u0.x); a1 += w0 * bf2f(u0.y); a2 += w0 * bf2f(u0.z); a3 += w0 * bf2f(u0.w);
    c0_ += w1 * bf2f(u1.x); c1_ += w1 * bf2f(u1.y); c2_ += w1 * bf2f(u1.z); c3_ += w1 * bf2f(u1.w);
    a0 += w2 * bf2f(u2.x); a1 += w2 * bf2f(u2.y); a2 += w2 * bf2f(u2.z); a3 += w2 * bf2f(u2.w);
    c0_ += w3 * bf2f(u3.x); c1_ += w3 * bf2f(u3.y); c2_ += w3 * bf2f(u3.z); c3_ += w3 * bf2f(u3.w);
  }
  for (; e < e1; e++) {
    int s = col[e];
    float c = coef[e];
    ushort4 u = *(const ushort4*)(XW + s * 256 + f4);
    a0 += c * bf2f(u.x); a1 += c * bf2f(u.y); a2 += c * bf2f(u.z); a3 += c * bf2f(u.w);
  }
  a0 += c0_; a1 += c1_; a2 += c2_; a3 += c3_;
  ushort4 bb = *(const ushort4*)(bias + f4);
  a0 = fmaxf(a0 + bf2f(bb.x), 0.f);
  a1 = fmaxf(a1 + bf2f(bb.y), 0.f);
  a2 = fmaxf(a2 + bf2f(bb.z), 0.f);
  a3 = fmaxf(a3 + bf2f(bb.w), 0.f);
  ushort4 o; o.x = f2bf(a0); o.y = f2bf(a1); o.z = f2bf(a2); o.w = f2bf(a3);
  *(ushort4*)(H + i * 256 + f4) = o;
}

// s[f] = sum_j c_j * H[j][f],  c_j = dinv_j*(t_j + dinv_j)  (layer-3 shortcut)
__global__ __launch_bounds__(256) void colsum_kernel(
    const ushort* __restrict__ H0, const ushort* __restrict__ H1,
    const float* __restrict__ dinv0, const float* __restrict__ dinv1,
    const float* __restrict__ t0, const float* __restrict__ t1,
    float* __restrict__ s0, float* __restrict__ s1) {
  int b = blockIdx.y;
  const ushort* H = b ? H1 : H0;
  const float* dinv = b ? dinv1 : dinv0;
  const float* t = b ? t1 : t0;
  float* s = b ? s1 : s0;
  int f = threadIdx.x;
  float acc = 0.f;
  for (int j = blockIdx.x; j < N_NODES; j += gridDim.x) {
    float dj = dinv[j];
    float c = dj * (t[j] + dj);
    acc += c * bf2f(H[j * 256 + f]);
  }
  atomicAdd(&s[f], acc);
}

// pooled = ((s0+s1) @ W3)/(2N) + b3 ;  out = pooled @ Wl + bl
__global__ __launch_bounds__(256) void final_kernel(
    const float* __restrict__ s0, const float* __restrict__ s1,
    const ushort* __restrict__ W3, const ushort* __restrict__ b3,
    const ushort* __restrict__ Wl, const ushort* __restrict__ bl,
    void* __restrict__ out, const int* __restrict__ flags) {
  __shared__ float v[256];
  __shared__ float pooled[256];
  int t = threadIdx.x;
  v[t] = s0[t] + s1[t];
  __syncthreads();
  float acc = 0.f;
  for (int f = 0; f < 256; f++) acc += v[f] * bf2f(W3[f * 256 + t]);
  pooled[t] = acc * (1.0f / (2.0f * N_NODES)) + bf2f(b3[t]);
  __syncthreads();
  if (t < 5) {
    float o = bf2f(bl[t]);
    for (int h = 0; h < 256; h++) o += pooled[h] * bf2f(Wl[h * 5 + t]);
    if (flags[0]) ((float*)out)[t] = o;
    else ((ushort*)out)[t] = f2bf(o);
  }
}

extern "C" void kernel_launch(void* const* d_in, const int* in_sizes, int n_in,
                              void* d_out, int out_size, void* d_ws, size_t ws_size,
                              hipStream_t stream) {
  const void* x1 = d_in[0];
  const void* ei1 = d_in[1];
  const void* x2 = d_in[2];
  const void* ei2 = d_in[3];
  const void* W1 = d_in[4];
  const void* b1 = d_in[5];
  const void* W2 = d_in[6];
  const void* b2 = d_in[7];
  const void* W3 = d_in[8];
  const void* b3 = d_in[9];
  const void* Wl = d_in[10];
  const void* bl = d_in[11];

  char* p = (char*)d_ws;
  auto alloc = [&](size_t bytes) {
    char* r = p;
    p += (bytes + 255) & ~size_t(255);
    return r;
  };
  int* flags   = (int*)alloc(256);
  float* dinv0 = (float*)alloc(N_NODES * 4);
  float* dinv1 = (float*)alloc(N_NODES * 4);
  float* t0    = (float*)alloc(N_NODES * 4);
  float* t1    = (float*)alloc(N_NODES * 4);
  float* s0    = (float*)alloc(HID * 4);
  float* s1    = (float*)alloc(HID * 4);
  int* cnt0    = (int*)alloc(N_NODES * 4);
  int* cnt1    = (int*)alloc(N_NODES * 4);
  int* rp0     = (int*)alloc((N_NODES + 1) * 4);
  int* rp1     = (int*)alloc((N_NODES + 1) * 4);
  int* col0    = (int*)alloc(N_EDGES * 4);
  int* col1    = (int*)alloc(N_EDGES * 4);
  float* coef0 = (float*)alloc(N_EDGES * 4);
  float* coef1 = (float*)alloc(N_EDGES * 4);
  ushort* wbuf = (ushort*)alloc(198661 * 2);
  ushort* xw0  = (ushort*)alloc((size_t)N_NODES * HID * 2);
  ushort* xw1  = (ushort*)alloc((size_t)N_NODES * HID * 2);
  ushort* xc0  = (ushort*)alloc((size_t)N_NODES * HID * 2);
  ushort* xc1  = (ushort*)alloc((size_t)N_NODES * HID * 2);
  // Lifetime-based aliasing: ei32+rank live only until fill_kernel; xw0 is
  // first written by gemm1 (after fill). 2*2.56 + 2*1.28 = 7.7MB <= 10.2MB.
  int* ei32_0 = (int*)xw0;
  int* ei32_1 = ei32_0 + 2 * N_EDGES;
  int* rank0  = ei32_1 + 2 * N_EDGES;
  int* rank1  = rank0 + N_EDGES;
  // xc dead after gemm1 reads it; h first written by agg1 (after gemm1).
  ushort* h0 = xc0;
  ushort* h1 = xc1;

  ushort* Wc1 = wbuf + 0;
  ushort* Wc2 = wbuf + 65536;
  ushort* Wc3 = wbuf + 131072;
  ushort* Wlc = wbuf + 196608;
  ushort* bc1 = wbuf + 197888;
  ushort* bc2 = wbuf + 198144;
  ushort* bc3 = wbuf + 198400;
  ushort* blc = wbuf + 198656;

  // --- dtype detection + canonicalization + graph prep ---
  detect_kernel<<<1, 256, 0, stream>>>(x1, ei1, flags);
  init_kernel<<<(N_NODES + 255) / 256, 256, 0, stream>>>(cnt0, cnt1, t0, t1, s0, s1);
  cvt_ei_count_kernel<<<dim3((2 * N_EDGES + 255) / 256, 2), 256, 0, stream>>>(
      ei1, ei2, ei32_0, ei32_1, cnt0, cnt1, rank0, rank1, flags);
  cvt_x_kernel<<<dim3(N_NODES * HID / 1024, 2), 256, 0, stream>>>(
      x1, x2, xc0, xc1, flags);
  cvt_w_kernel<<<(198661 + 255) / 256, 256, 0, stream>>>(
      W1, W2, W3, Wl, b1, b2, b3, bl, wbuf, flags);
  dinv_kernel<<<dim3((N_NODES + 255) / 256, 2), 256, 0, stream>>>(cnt0, cnt1, dinv0, dinv1);
  scan_kernel<<<2, 1024, 0, stream>>>(cnt0, cnt1, rp0, rp1);
  fill_kernel<<<dim3((N_EDGES + 255) / 256, 2), 256, 0, stream>>>(
      ei32_0, ei32_1, dinv0, dinv1, rp0, rp1, rank0, rank1, col0, col1, coef0, coef1, t0, t1);

  // Layer 1: xw = x @ W1 ; h = relu(agg(xw) + b1)
  gemm_kernel<<<dim3(313, 4, 2), 256, 0, stream>>>(xc0, xc1, Wc1, xw0, xw1);
  agg_kernel<<<dim3(N_NODES / 4, 2), 256, 0, stream>>>(
      xw0, xw1, dinv0, dinv1, rp0, rp1, col0, col1, coef0, coef1, bc1, h0, h1);

  // Layer 2: xw = h @ W2 ; h = relu(agg(xw) + b2)
  gemm_kernel<<<dim3(313, 4, 2), 256, 0, stream>>>(h0, h1, Wc2, xw0, xw1);
  agg_kernel<<<dim3(N_NODES / 4, 2), 256, 0, stream>>>(
      xw0, xw1, dinv0, dinv1, rp0, rp1, col0, col1, coef0, coef1, bc2, h0, h1);

  // Layer 3 + pool, collapsed: s = sum_j c_j h2_j ; out = ((s0+s1)W3/(2N)+b3) @ Wl + bl
  colsum_kernel<<<dim3(128, 2), 256, 0, stream>>>(h0, h1, dinv0, dinv1, t0, t1, s0, s1);
  final_kernel<<<1, 256, 0, stream>>>(s0, s1, Wc3, bc3, Wlc, blc, d_out, flags);
}